// Round 10
// baseline (268.256 us; speedup 1.0000x reference)
//
#include <hip/hip_runtime.h>

typedef unsigned short u16;
typedef __attribute__((ext_vector_type(8))) short short8;
typedef __attribute__((ext_vector_type(4))) float floatx4;

#define AS1 __attribute__((address_space(1)))
#define AS3 __attribute__((address_space(3)))

__device__ __forceinline__ u16 f2bf(float f) {
  unsigned u = __float_as_uint(f);
  u += 0x7fffu + ((u >> 16) & 1u);
  return (u16)(u >> 16);
}

// device-scope grid barrier; counters zeroed by hipMemsetAsync each launch.
// Safe: grid 256, 1 block/CU (LDS 74 KB), capacity >= grid -> all resident.
__device__ __forceinline__ void gridbar(unsigned* bar, int idx) {
  __syncthreads();
  if (threadIdx.x == 0) {
    __threadfence();  // agent release: prior stores -> coherence point
    __hip_atomic_fetch_add(bar + idx, 1u, __ATOMIC_ACQ_REL, __HIP_MEMORY_SCOPE_AGENT);
    while (__hip_atomic_load(bar + idx, __ATOMIC_ACQUIRE, __HIP_MEMORY_SCOPE_AGENT) < 256u)
      __builtin_amdgcn_s_sleep(1);
  }
  __syncthreads();
  // per-thread acquire: invalidate this CU's caches for cross-block data
  (void)__hip_atomic_load(bar + idx, __ATOMIC_ACQUIRE, __HIP_MEMORY_SCOPE_AGENT);
}

__global__ __launch_bounds__(512) void fused_all(
    const float* __restrict__ x,
    const float* __restrict__ Wq, const float* __restrict__ bq,
    const float* __restrict__ Wk, const float* __restrict__ bk,
    const float* __restrict__ Wv, const float* __restrict__ bv,
    const float* __restrict__ gamma, const float* __restrict__ beta,
    u16* __restrict__ h, u16* __restrict__ wqkv, float* __restrict__ partials,
    unsigned* __restrict__ bar,
    u16* __restrict__ qb, u16* __restrict__ kb, u16* __restrict__ vT,
    float* __restrict__ outf) {
  __shared__ union {
    struct { float red[16]; } p0;
    struct { float tile[64][65]; float stats[2]; } gn;
    struct { u16 As[16384]; u16 Bs[16384]; } mm;                       // 32+32 KB
    struct { u16 Ks[16384]; u16 Vs[16384]; u16 Ps[4096]; float lpart[2][64]; } fa; // 74.2 KB
  } S;

  int blk = blockIdx.x, t = threadIdx.x;
  int w = t >> 6, lane = t & 63;
  int q = lane >> 4, r16 = lane & 15;

  // ===== Phase 0: weight convert + gn partials ===============================
  for (int e = t; e < 768; e += 512) {
    int row = blk * 3 + (e >> 8);
    int col = e & 255;
    const float* src = row < 256 ? Wq + row * 256
                     : row < 512 ? Wk + (row - 256) * 256
                                 : Wv + (row - 512) * 256;
    wqkv[row * 256 + col] = f2bf(src[col]);
  }
  for (int i = 0; i < 4; ++i) {
    int sp = blk * 4 + i;  // 0..1023: group g = sp>>4, part = sp&15
    const float4* b4 = (const float4*)(x + (size_t)(sp >> 4) * 65536 + (sp & 15) * 4096);
    float s = 0.f, s2 = 0.f;
#pragma unroll
    for (int j = 0; j < 2; ++j) {
      float4 v = b4[j * 512 + t];
      s += v.x + v.y + v.z + v.w;
      s2 += v.x * v.x + v.y * v.y + v.z * v.z + v.w * v.w;
    }
    for (int off = 32; off; off >>= 1) { s += __shfl_xor(s, off); s2 += __shfl_xor(s2, off); }
    if (lane == 0) { S.p0.red[w] = s; S.p0.red[8 + w] = s2; }
    __syncthreads();
    if (t == 0) {
      float ts = 0.f, ts2 = 0.f;
      for (int k = 0; k < 8; ++k) { ts += S.p0.red[k]; ts2 += S.p0.red[8 + k]; }
      partials[sp * 2] = ts;
      partials[sp * 2 + 1] = ts2;
    }
    __syncthreads();
  }
  gridbar(bar, 0);

  // ===== Phase 1: groupnorm apply + transpose -> h[b][p][c] ==================
  {
    int b = blk >> 4, grp = (blk >> 2) & 3, pq = blk & 3;
    int c0 = grp * 64;
    if (t < 16) {
      int g = b * 4 + grp;
      float s = partials[(g * 16 + t) * 2];
      float s2 = partials[(g * 16 + t) * 2 + 1];
      for (int off = 8; off; off >>= 1) {
        s += __shfl_xor(s, off, 16);
        s2 += __shfl_xor(s2, off, 16);
      }
      if (t == 0) {
        float mean = s * (1.f / 65536.f);
        float var = s2 * (1.f / 65536.f) - mean * mean;
        S.gn.stats[0] = mean;
        S.gn.stats[1] = rsqrtf(var + 1e-5f);
      }
    }
    __syncthreads();
    float mean = S.gn.stats[0], rstd = S.gn.stats[1];
    int c = t >> 3, p8 = (t & 7) * 8;
    float gm = gamma[c0 + c] * rstd;
    float bt = beta[c0 + c] - mean * gm;
    int pr = t >> 3, c8 = t & 7;
    for (int i = 0; i < 4; ++i) {
      int p0 = pq * 256 + i * 64;
      const float* xp = x + ((size_t)(b * 256 + c0 + c)) * 1024 + p0 + p8;
      float4 a = *(const float4*)xp;
      float4 bb = *(const float4*)(xp + 4);
      S.gn.tile[c][p8 + 0] = a.x * gm + bt;
      S.gn.tile[c][p8 + 1] = a.y * gm + bt;
      S.gn.tile[c][p8 + 2] = a.z * gm + bt;
      S.gn.tile[c][p8 + 3] = a.w * gm + bt;
      S.gn.tile[c][p8 + 4] = bb.x * gm + bt;
      S.gn.tile[c][p8 + 5] = bb.y * gm + bt;
      S.gn.tile[c][p8 + 6] = bb.z * gm + bt;
      S.gn.tile[c][p8 + 7] = bb.w * gm + bt;
      __syncthreads();
      union { u16 us[8]; uint4 v4; } tmp;
#pragma unroll
      for (int j = 0; j < 8; ++j) tmp.us[j] = f2bf(S.gn.tile[c8 * 8 + j][pr]);
      *(uint4*)(h + ((size_t)(b * 1024 + p0 + pr)) * 256 + c0 + c8 * 8) = tmp.v4;
      __syncthreads();
    }
  }
  gridbar(bar, 1);

  // ===== Phase 2: QKV GEMM, A-stationary in registers ========================
  // block owns (b, 64-row m-tile); A staged once, A-frags in VGPRs; 12 n-tiles
  {
    int b = blk >> 4, m0 = (blk & 15) * 64;
    int wm = w & 1, wn = w >> 1;  // wave tile: 32 rows x 16 cols
    // stage A (64 x 256 bf16 = 32 KB), chunk-major [kc 32][row 64][8]
#pragma unroll
    for (int i = 0; i < 4; ++i) {
      int ub = i * 512 + w * 64;
      int u = ub + lane;  // row = u&63 (=lane), kc = u>>6 (uniform)
      __builtin_amdgcn_global_load_lds(
          (const AS1 void*)(h + ((size_t)(b * 1024 + m0 + (u & 63))) * 256 + (u >> 6) * 8),
          (AS3 void*)(S.mm.As + (size_t)ub * 8), 16, 0, 0);
    }
    __syncthreads();
    short8 afr[8][2];
#pragma unroll
    for (int ks = 0; ks < 8; ++ks)
#pragma unroll
      for (int mi = 0; mi < 2; ++mi)
        afr[ks][mi] = *(const short8*)(
            S.mm.As + (size_t)((ks * 4 + q) * 64 + wm * 32 + mi * 16 + r16) * 8);

    for (int nt = 0; nt < 12; ++nt) {
      __syncthreads();  // prev n-tile's Bs reads done
#pragma unroll
      for (int i = 0; i < 4; ++i) {
        int ub = i * 512 + w * 64;
        int u = ub + lane;
        __builtin_amdgcn_global_load_lds(
            (const AS1 void*)(wqkv + ((size_t)(nt * 64 + (u & 63))) * 256 + (u >> 6) * 8),
            (AS3 void*)(S.mm.Bs + (size_t)ub * 8), 16, 0, 0);
      }
      __syncthreads();  // B landed
      floatx4 acc[2];
      acc[0] = (floatx4)0.f;
      acc[1] = (floatx4)0.f;
#pragma unroll
      for (int ks = 0; ks < 8; ++ks) {
        short8 bf = *(const short8*)(
            S.mm.Bs + (size_t)((ks * 4 + q) * 64 + wn * 16 + r16) * 8);
        acc[0] = __builtin_amdgcn_mfma_f32_16x16x32_bf16(afr[ks][0], bf, acc[0], 0, 0, 0);
        acc[1] = __builtin_amdgcn_mfma_f32_16x16x32_bf16(afr[ks][1], bf, acc[1], 0, 0, 0);
      }
      int dcol = nt * 64 + wn * 16 + r16;  // 0..767
      float bv_ = dcol < 256 ? bq[dcol] : dcol < 512 ? bk[dcol - 256] : bv[dcol - 512];
#pragma unroll
      for (int mi = 0; mi < 2; ++mi)
#pragma unroll
        for (int rg = 0; rg < 4; ++rg) {
          int row = m0 + wm * 32 + mi * 16 + q * 4 + rg;
          u16 hv = f2bf(acc[mi][rg] + bv_);
          if (nt < 4)
            qb[((size_t)b * 1024 + row) * 256 + dcol] = hv;
          else if (nt < 8)
            kb[((size_t)b * 1024 + row) * 256 + (dcol - 256)] = hv;
          else
            vT[((size_t)b * 256 + (dcol - 512)) * 1024 + row] = hv;  // vT[d][n]
        }
    }
  }
  gridbar(bar, 2);

  // ===== Phase 3: flash attention (v5 verbatim, 58.9 us structure) ===========
  {
    int b = (blk & 7) | ((blk >> 7) << 3);  // XCD swizzle
    int qt = (blk >> 3) & 15;
    int m0 = qt * 64;
    int wq = w & 3;   // S-phase row-group
    int kh = w >> 2;  // S-phase key-half
    const u16* Qb = qb + ((size_t)b * 1024 + m0) * 256;
    const u16* Kb = kb + (size_t)b * 262144;
    const u16* Vb = vT + (size_t)b * 262144;

#pragma unroll
    for (int i = 0; i < 4; ++i)
      __builtin_amdgcn_global_load_lds(
          (const AS1 void*)(Kb + (size_t)lane * 256 + (i * 8 + w) * 8),
          (AS3 void*)(S.fa.Ks + ((i * 8 + w) * 64) * 8), 16, 0, 0);

    short8 qf[8];
#pragma unroll
    for (int ks = 0; ks < 8; ++ks)
      qf[ks] = *(const short8*)(Qb + (size_t)(wq * 16 + r16) * 256 + ks * 32 + q * 8);

    __syncthreads();  // K(0) landed

    float l_acc[4] = {0.f, 0.f, 0.f, 0.f};
    floatx4 acc_o[4][2];
#pragma unroll
    for (int i = 0; i < 4; ++i)
#pragma unroll
      for (int j = 0; j < 2; ++j) acc_o[i][j] = (floatx4)0.f;

    const float cexp = 0.0625f * 1.44269504f;

    for (int jt = 0; jt < 16; ++jt) {
      int j0 = jt * 64;
#pragma unroll
      for (int i = 0; i < 4; ++i) {
        int u0 = (i * 8 + w) * 64;
        int jc = u0 >> 8, d0 = u0 & 255;
        __builtin_amdgcn_global_load_lds(
            (const AS1 void*)(Vb + (size_t)(d0 + lane) * 1024 + j0 + jc * 8),
            (AS3 void*)(S.fa.Vs + (size_t)u0 * 8), 16, 0, 0);
      }

      floatx4 acc_s[2];
      acc_s[0] = (floatx4)0.f;
      acc_s[1] = (floatx4)0.f;
#pragma unroll
      for (int ks = 0; ks < 8; ++ks) {
#pragma unroll
        for (int ni = 0; ni < 2; ++ni) {
          short8 bf = *(const short8*)(
              S.fa.Ks + (size_t)((ks * 4 + q) * 64 + kh * 32 + ni * 16 + r16) * 8);
          acc_s[ni] = __builtin_amdgcn_mfma_f32_16x16x32_bf16(qf[ks], bf, acc_s[ni], 0, 0, 0);
        }
      }

#pragma unroll
      for (int ni = 0; ni < 2; ++ni)
#pragma unroll
        for (int rg = 0; rg < 4; ++rg) {
          float p = exp2f(acc_s[ni][rg] * cexp);
          l_acc[rg] += p;
          int jc = kh * 4 + ni * 2 + (r16 >> 3);
          S.fa.Ps[(size_t)(jc * 64 + wq * 16 + q * 4 + rg) * 8 + (r16 & 7)] = f2bf(p);
        }

      __syncthreads();  // mid: V(jt)+Ps visible; Ks(jt) reads done

      if (jt < 15) {
#pragma unroll
        for (int i = 0; i < 4; ++i)
          __builtin_amdgcn_global_load_lds(
              (const AS1 void*)(Kb + (size_t)(j0 + 64 + lane) * 256 + (i * 8 + w) * 8),
              (AS3 void*)(S.fa.Ks + ((i * 8 + w) * 64) * 8), 16, 0, 0);
      }

#pragma unroll
      for (int ks2 = 0; ks2 < 2; ++ks2) {
        short8 af[4];
#pragma unroll
        for (int mi = 0; mi < 4; ++mi)
          af[mi] = *(const short8*)(S.fa.Ps + (size_t)((ks2 * 4 + q) * 64 + mi * 16 + r16) * 8);
#pragma unroll
        for (int ni2 = 0; ni2 < 2; ++ni2) {
          short8 bf = *(const short8*)(
              S.fa.Vs + (size_t)((ks2 * 4 + q) * 256 + w * 32 + ni2 * 16 + r16) * 8);
#pragma unroll
          for (int mi = 0; mi < 4; ++mi)
            acc_o[mi][ni2] = __builtin_amdgcn_mfma_f32_16x16x32_bf16(af[mi], bf, acc_o[mi][ni2], 0, 0, 0);
        }
      }
      __syncthreads();  // end: K(jt+1) landed; Vs/Ps reads done
    }

#pragma unroll
    for (int rg = 0; rg < 4; ++rg) {
      float l = l_acc[rg];
      l += __shfl_xor(l, 1);
      l += __shfl_xor(l, 2);
      l += __shfl_xor(l, 4);
      l += __shfl_xor(l, 8);
      if (r16 == 0) S.fa.lpart[kh][wq * 16 + q * 4 + rg] = l;
    }
    __syncthreads();

#pragma unroll
    for (int mi = 0; mi < 4; ++mi) {
      float inv[4];
#pragma unroll
      for (int rg = 0; rg < 4; ++rg) {
        int row = mi * 16 + q * 4 + rg;
        inv[rg] = 1.f / (S.fa.lpart[0][row] + S.fa.lpart[1][row]);
      }
#pragma unroll
      for (int ni2 = 0; ni2 < 2; ++ni2) {
        int d = w * 32 + ni2 * 16 + r16;
        size_t go = ((size_t)b * 256 + d) * 1024 + m0 + mi * 16 + q * 4;
        float4 xv = *(const float4*)(x + go);
        float4 o;
        o.x = acc_o[mi][ni2][0] * inv[0] + xv.x;
        o.y = acc_o[mi][ni2][1] * inv[1] + xv.y;
        o.z = acc_o[mi][ni2][2] * inv[2] + xv.z;
        o.w = acc_o[mi][ni2][3] * inv[3] + xv.w;
        *(float4*)(outf + go) = o;
      }
    }
  }
}

extern "C" void kernel_launch(void* const* d_in, const int* in_sizes, int n_in,
                              void* d_out, int out_size, void* d_ws, size_t ws_size,
                              hipStream_t stream) {
  (void)in_sizes; (void)n_in; (void)out_size; (void)ws_size;
  const float* x     = (const float*)d_in[0];
  const float* Wq    = (const float*)d_in[1];
  const float* bq    = (const float*)d_in[2];
  const float* Wk    = (const float*)d_in[3];
  const float* bk    = (const float*)d_in[4];
  const float* Wv    = (const float*)d_in[5];
  const float* bv    = (const float*)d_in[6];
  const float* gamma = (const float*)d_in[7];
  const float* beta  = (const float*)d_in[8];
  float* out = (float*)d_out;
  char* ws = (char*)d_ws;

  u16*      h        = (u16*)(ws);                                // 8 MiB
  u16*      wqkv     = (u16*)(ws + (8u << 20));                   // 384 KiB
  float*    partials = (float*)(ws + (8u << 20) + (512u << 10));  // 8 KiB
  unsigned* bar      = (unsigned*)(ws + (8u << 20) + (640u << 10)); // 64 B
  u16*      qb       = (u16*)(ws + (16u << 20));                  // 8 MiB
  u16*      kb       = (u16*)(ws + (24u << 20));                  // 8 MiB
  u16*      vT       = (u16*)(ws + (32u << 20));                  // 8 MiB

  hipMemsetAsync(bar, 0, 64, stream);
  hipLaunchKernelGGL(fused_all, dim3(256), dim3(512), 0, stream,
                     x, Wq, bq, Wk, bk, Wv, bv, gamma, beta,
                     h, wqkv, partials, bar, qb, kb, vT, out);
}

// Round 11
// 168.590 us; speedup vs baseline: 1.5912x; 1.5912x over previous
//
#include <hip/hip_runtime.h>

typedef unsigned short u16;
typedef __attribute__((ext_vector_type(8))) short short8;
typedef __attribute__((ext_vector_type(4))) float floatx4;

#define AS1 __attribute__((address_space(1)))
#define AS3 __attribute__((address_space(3)))

__device__ __forceinline__ u16 f2bf(float f) {
  unsigned u = __float_as_uint(f);
  u += 0x7fffu + ((u >> 16) & 1u);
  return (u16)(u >> 16);
}

// ---- prep: blocks [0,769) = weight/bias convert; [769,1793) = gn partials --
__global__ void prep(const float* __restrict__ Wq, const float* __restrict__ Wk,
                     const float* __restrict__ Wv, const float* __restrict__ bq,
                     const float* __restrict__ bk, const float* __restrict__ bv,
                     u16* __restrict__ wqkv, float* __restrict__ bqkv,
                     const float* __restrict__ x, float* __restrict__ partials) {
  int bid = blockIdx.x, t = threadIdx.x;
  if (bid < 768) {
    const float* src = bid < 256 ? Wq + bid * 256
                     : bid < 512 ? Wk + (bid - 256) * 256
                                 : Wv + (bid - 512) * 256;
    wqkv[bid * 256 + t] = f2bf(src[t]);
    return;
  }
  if (bid == 768) {
    for (int i = 0; i < 3; ++i) {
      int d = i * 256 + t;
      float v = d < 256 ? bq[d] : d < 512 ? bk[d - 256] : bv[d - 512];
      bqkv[d] = v;
    }
    return;
  }
  int pb = bid - 769;             // 0..1023
  int g = pb >> 4, part = pb & 15;
  const float4* b4 = (const float4*)(x + (size_t)g * 65536 + part * 4096);
  float s = 0.f, s2 = 0.f;
  for (int i = 0; i < 4; ++i) {
    float4 v = b4[i * 256 + t];
    s += v.x + v.y + v.z + v.w;
    s2 += v.x * v.x + v.y * v.y + v.z * v.z + v.w * v.w;
  }
  for (int off = 32; off; off >>= 1) {
    s += __shfl_xor(s, off);
    s2 += __shfl_xor(s2, off);
  }
  __shared__ float red[8];
  int wave = t >> 6, lane = t & 63;
  if (lane == 0) { red[wave] = s; red[4 + wave] = s2; }
  __syncthreads();
  if (t == 0) {
    partials[pb * 2]     = red[0] + red[1] + red[2] + red[3];
    partials[pb * 2 + 1] = red[4] + red[5] + red[6] + red[7];
  }
}

// ------- groupnorm apply + transpose: h[b][p][c] bf16 (64x64 LDS tiles) -----
__global__ void gn_apply(const float* __restrict__ x, const float* __restrict__ gamma,
                         const float* __restrict__ beta, const float* __restrict__ partials,
                         u16* __restrict__ h) {
  __shared__ float tile[64][65];
  __shared__ float s_stats[2];
  int p0 = blockIdx.x * 64, c0 = blockIdx.y * 64, b = blockIdx.z;
  int t = threadIdx.x;
  int g = b * 4 + blockIdx.y;
  if (t < 16) {
    float s  = partials[(g * 16 + t) * 2];
    float s2 = partials[(g * 16 + t) * 2 + 1];
    for (int off = 8; off; off >>= 1) {
      s += __shfl_xor(s, off, 16);
      s2 += __shfl_xor(s2, off, 16);
    }
    if (t == 0) {
      float mean = s * (1.f / 65536.f);
      float var = s2 * (1.f / 65536.f) - mean * mean;
      s_stats[0] = mean;
      s_stats[1] = rsqrtf(var + 1e-5f);
    }
  }
  __syncthreads();
  float mean = s_stats[0], rstd = s_stats[1];
  int cl = t >> 4, p4 = t & 15;
  for (int i = 0; i < 4; ++i) {
    int c = cl + i * 16;
    float gm = gamma[c0 + c] * rstd;
    float bt = beta[c0 + c] - mean * gm;
    float4 v = *(const float4*)(x + ((size_t)(b * 256 + c0 + c)) * 1024 + p0 + p4 * 4);
    tile[c][p4 * 4 + 0] = v.x * gm + bt;
    tile[c][p4 * 4 + 1] = v.y * gm + bt;
    tile[c][p4 * 4 + 2] = v.z * gm + bt;
    tile[c][p4 * 4 + 3] = v.w * gm + bt;
  }
  __syncthreads();
  int pr = t >> 3, c8 = t & 7;
  for (int i = 0; i < 2; ++i) {
    int p = pr + i * 32;
    union { u16 us[8]; uint4 v4; } tmp;
    for (int j = 0; j < 8; ++j) tmp.us[j] = f2bf(tile[c8 * 8 + j][p]);
    *(uint4*)(h + ((size_t)(b * 1024 + p0 + p)) * 256 + c0 + c8 * 8) = tmp.v4;
  }
}

// ---------------- QKV GEMM v2: 128x128x32 tiles, 512 threads ----------------
// The v5 lesson applied: same staging volume + 2-barrier kstep, but 8 waves
// (wave = row-half x 32-col stripe) -> ~90 VGPR, 16 KB LDS, 2 blocks/CU
// co-resident = 4 waves/SIMD; per-wave serial chain halves (6 ds_read+8 MFMA
// per interval). DMA: 1 A-unit + 1 B-unit per thread (kc=w>>1, row=(w&1)*64+lane).
__global__ __launch_bounds__(512) void gemm_qkv(
    const u16* __restrict__ A, const u16* __restrict__ B,
    const float* __restrict__ bias,
    u16* __restrict__ o0, u16* __restrict__ o1, u16* __restrict__ o2) {
  __shared__ u16 As[4 * 128 * 8];  // 8 KB, chunk-major [kc 4][row 128][8]
  __shared__ u16 Bs[4 * 128 * 8];  // 8 KB
  int b = blockIdx.z;
  int m0 = blockIdx.x * 128, n0 = blockIdx.y * 128;
  const u16* Ab = A + (size_t)b * 262144 + (size_t)m0 * 256;
  const u16* Bb = B + (size_t)n0 * 256;
  int t = threadIdx.x, w = t >> 6, lane = t & 63;
  int q = lane >> 4, r16 = lane & 15;
  int wm = w & 1, wn = w >> 1;     // wave tile: 64 rows x 32 cols

  floatx4 acc[4][2];
#pragma unroll
  for (int i = 0; i < 4; ++i)
#pragma unroll
    for (int j = 0; j < 2; ++j) acc[i][j] = (floatx4)0.f;

  int kc = w >> 1, row = (w & 1) * 64 + lane;  // staging unit (wave-uniform base)
  for (int ks = 0; ks < 8; ++ks) {
    int k0 = ks * 32;
    __syncthreads();
    __builtin_amdgcn_global_load_lds(
        (const AS1 void*)(Ab + (size_t)row * 256 + k0 + kc * 8),
        (AS3 void*)(As + (size_t)(w * 64) * 8), 16, 0, 0);
    __builtin_amdgcn_global_load_lds(
        (const AS1 void*)(Bb + (size_t)row * 256 + k0 + kc * 8),
        (AS3 void*)(Bs + (size_t)(w * 64) * 8), 16, 0, 0);
    __syncthreads();
    short8 af[4], bfr[2];
#pragma unroll
    for (int mi = 0; mi < 4; ++mi)
      af[mi] = *(const short8*)(As + (size_t)(q * 128 + wm * 64 + mi * 16 + r16) * 8);
#pragma unroll
    for (int ni = 0; ni < 2; ++ni)
      bfr[ni] = *(const short8*)(Bs + (size_t)(q * 128 + wn * 32 + ni * 16 + r16) * 8);
#pragma unroll
    for (int mi = 0; mi < 4; ++mi)
#pragma unroll
      for (int ni = 0; ni < 2; ++ni)
        acc[mi][ni] = __builtin_amdgcn_mfma_f32_16x16x32_bf16(af[mi], bfr[ni], acc[mi][ni], 0, 0, 0);
  }

#pragma unroll
  for (int ni = 0; ni < 2; ++ni) {
    int dcol = n0 + wn * 32 + ni * 16 + r16;
    float bv_ = bias[dcol];
#pragma unroll
    for (int mi = 0; mi < 4; ++mi)
#pragma unroll
      for (int rg = 0; rg < 4; ++rg) {
        int mrow = m0 + wm * 64 + mi * 16 + q * 4 + rg;
        u16 hv = f2bf(acc[mi][ni][rg] + bv_);
        if (dcol < 256)
          o0[((size_t)b * 1024 + mrow) * 256 + dcol] = hv;
        else if (dcol < 512)
          o1[((size_t)b * 1024 + mrow) * 256 + (dcol - 256)] = hv;
        else
          o2[((size_t)b * 256 + (dcol - 512)) * 1024 + mrow] = hv;  // vT[d][n]
      }
  }
}

// ---------------- fused flash attention v5 (58.9 us champion) ---------------
__global__ __launch_bounds__(512) void flash_attn(
    const u16* __restrict__ qb, const u16* __restrict__ kb,
    const u16* __restrict__ vT, const float* __restrict__ xres,
    float* __restrict__ outf) {
  __shared__ u16 Ks[16384];   // [c-chunk 32][key 64][8]   32 KB
  __shared__ u16 Vs[16384];   // [j-chunk 8][d 256][8]     32 KB
  __shared__ u16 Ps[4096];    // [j-chunk 8][qrow 64][8]    8 KB
  __shared__ float lpart[2][64];
  int idx = blockIdx.x;
  int b = (idx & 7) | ((idx >> 7) << 3);   // XCD swizzle: batch -> one XCD
  int qt = (idx >> 3) & 15;
  int m0 = qt * 64;
  int t = threadIdx.x, w = t >> 6, lane = t & 63;
  int q = lane >> 4, r16 = lane & 15;
  int wq = w & 3;       // S-phase row-group
  int kh = w >> 2;      // S-phase key-half
  const u16* Qb = qb + ((size_t)b * 1024 + m0) * 256;
  const u16* Kb = kb + (size_t)b * 262144;
  const u16* Vb = vT + (size_t)b * 262144;

#pragma unroll
  for (int i = 0; i < 4; ++i)
    __builtin_amdgcn_global_load_lds(
        (const AS1 void*)(Kb + (size_t)lane * 256 + (i * 8 + w) * 8),
        (AS3 void*)(Ks + ((i * 8 + w) * 64) * 8), 16, 0, 0);

  short8 qf[8];
#pragma unroll
  for (int ks = 0; ks < 8; ++ks)
    qf[ks] = *(const short8*)(Qb + (size_t)(wq * 16 + r16) * 256 + ks * 32 + q * 8);

  __syncthreads();  // K(0) landed

  float l_acc[4] = {0.f, 0.f, 0.f, 0.f};
  floatx4 acc_o[4][2];
#pragma unroll
  for (int i = 0; i < 4; ++i)
#pragma unroll
    for (int j = 0; j < 2; ++j) acc_o[i][j] = (floatx4)0.f;

  const float cexp = 0.0625f * 1.44269504f;

  for (int jt = 0; jt < 16; ++jt) {
    int j0 = jt * 64;
#pragma unroll
    for (int i = 0; i < 4; ++i) {
      int u0 = (i * 8 + w) * 64;
      int jc = u0 >> 8, d0 = u0 & 255;
      __builtin_amdgcn_global_load_lds(
          (const AS1 void*)(Vb + (size_t)(d0 + lane) * 1024 + j0 + jc * 8),
          (AS3 void*)(Vs + (size_t)u0 * 8), 16, 0, 0);
    }

    floatx4 acc_s[2];
    acc_s[0] = (floatx4)0.f;
    acc_s[1] = (floatx4)0.f;
#pragma unroll
    for (int ks = 0; ks < 8; ++ks) {
#pragma unroll
      for (int ni = 0; ni < 2; ++ni) {
        short8 bf = *(const short8*)(Ks + (size_t)((ks * 4 + q) * 64 + kh * 32 + ni * 16 + r16) * 8);
        acc_s[ni] = __builtin_amdgcn_mfma_f32_16x16x32_bf16(qf[ks], bf, acc_s[ni], 0, 0, 0);
      }
    }

#pragma unroll
    for (int ni = 0; ni < 2; ++ni)
#pragma unroll
      for (int rg = 0; rg < 4; ++rg) {
        float p = exp2f(acc_s[ni][rg] * cexp);
        l_acc[rg] += p;
        int jc = kh * 4 + ni * 2 + (r16 >> 3);
        Ps[(size_t)(jc * 64 + wq * 16 + q * 4 + rg) * 8 + (r16 & 7)] = f2bf(p);
      }

    __syncthreads();  // mid: V(jt)+Ps visible; Ks(jt) reads done

    if (jt < 15) {
#pragma unroll
      for (int i = 0; i < 4; ++i)
        __builtin_amdgcn_global_load_lds(
            (const AS1 void*)(Kb + (size_t)(j0 + 64 + lane) * 256 + (i * 8 + w) * 8),
            (AS3 void*)(Ks + ((i * 8 + w) * 64) * 8), 16, 0, 0);
    }

#pragma unroll
    for (int ks2 = 0; ks2 < 2; ++ks2) {
      short8 af[4];
#pragma unroll
      for (int mi = 0; mi < 4; ++mi)
        af[mi] = *(const short8*)(Ps + (size_t)((ks2 * 4 + q) * 64 + mi * 16 + r16) * 8);
#pragma unroll
      for (int ni2 = 0; ni2 < 2; ++ni2) {
        short8 bf = *(const short8*)(Vs + (size_t)((ks2 * 4 + q) * 256 + w * 32 + ni2 * 16 + r16) * 8);
#pragma unroll
        for (int mi = 0; mi < 4; ++mi)
          acc_o[mi][ni2] = __builtin_amdgcn_mfma_f32_16x16x32_bf16(af[mi], bf, acc_o[mi][ni2], 0, 0, 0);
      }
    }
    __syncthreads();  // end: K(jt+1) landed; Vs/Ps reads done
  }

#pragma unroll
  for (int rg = 0; rg < 4; ++rg) {
    float l = l_acc[rg];
    l += __shfl_xor(l, 1);
    l += __shfl_xor(l, 2);
    l += __shfl_xor(l, 4);
    l += __shfl_xor(l, 8);
    if (r16 == 0) lpart[kh][wq * 16 + q * 4 + rg] = l;
  }
  __syncthreads();

#pragma unroll
  for (int mi = 0; mi < 4; ++mi) {
    float inv[4];
#pragma unroll
    for (int rg = 0; rg < 4; ++rg) {
      int row = mi * 16 + q * 4 + rg;
      inv[rg] = 1.f / (lpart[0][row] + lpart[1][row]);
    }
#pragma unroll
    for (int ni2 = 0; ni2 < 2; ++ni2) {
      int d = w * 32 + ni2 * 16 + r16;
      size_t go = ((size_t)b * 256 + d) * 1024 + m0 + mi * 16 + q * 4;
      float4 xv = *(const float4*)(xres + go);
      float4 o;
      o.x = acc_o[mi][ni2][0] * inv[0] + xv.x;
      o.y = acc_o[mi][ni2][1] * inv[1] + xv.y;
      o.z = acc_o[mi][ni2][2] * inv[2] + xv.z;
      o.w = acc_o[mi][ni2][3] * inv[3] + xv.w;
      *(float4*)(outf + go) = o;
    }
  }
}

extern "C" void kernel_launch(void* const* d_in, const int* in_sizes, int n_in,
                              void* d_out, int out_size, void* d_ws, size_t ws_size,
                              hipStream_t stream) {
  (void)in_sizes; (void)n_in; (void)out_size; (void)ws_size;
  const float* x     = (const float*)d_in[0];
  const float* Wq    = (const float*)d_in[1];
  const float* bq    = (const float*)d_in[2];
  const float* Wk    = (const float*)d_in[3];
  const float* bk    = (const float*)d_in[4];
  const float* Wv    = (const float*)d_in[5];
  const float* bv    = (const float*)d_in[6];
  const float* gamma = (const float*)d_in[7];
  const float* beta  = (const float*)d_in[8];
  float* out = (float*)d_out;
  char* ws = (char*)d_ws;

  u16*   h      = (u16*)(ws);                                  // 8 MiB
  u16*   wqkv   = (u16*)(ws + (8u << 20));                     // 384 KiB
  float* bqkv   = (float*)(ws + (8u << 20) + (384u << 10));    // 3 KiB
  float* statsP = (float*)(ws + (8u << 20) + (400u << 10));    // 8 KiB
  u16*   qb     = (u16*)(ws + (9u << 20));                     // 8 MiB
  u16*   kb     = (u16*)(ws + (17u << 20));                    // 8 MiB
  u16*   vT     = (u16*)(ws + (25u << 20));                    // 8 MiB

  hipLaunchKernelGGL(prep, dim3(1793), dim3(256), 0, stream,
                     Wq, Wk, Wv, bq, bk, bv, wqkv, bqkv, x, statsP);
  hipLaunchKernelGGL(gn_apply, dim3(16, 4, 16), dim3(256), 0, stream,
                     x, gamma, beta, statsP, h);
  hipLaunchKernelGGL(gemm_qkv, dim3(8, 6, 16), dim3(512), 0, stream,
                     h, wqkv, bqkv, qb, kb, vT);
  hipLaunchKernelGGL(flash_attn, dim3(256), dim3(512), 0, stream, qb, kb, vT, x, out);
}